// Round 18
// baseline (1494.649 us; speedup 1.0000x reference)
//
#include <hip/hip_runtime.h>
#include <hip/hip_bf16.h>
#include <cmath>

#define T_STEPS 50
#define BATCH   8192
#define ROWS    32                 // rows per block
#define NBLK    (BATCH / ROWS)     // 256 blocks
#define THREADS 512                // 8 waves

typedef float  f32x4  __attribute__((ext_vector_type(4)));
typedef __bf16 bf16x8 __attribute__((ext_vector_type(8)));
typedef unsigned int u32x4 __attribute__((ext_vector_type(4)));
typedef unsigned short u16x4 __attribute__((ext_vector_type(4)));

// ---- packed weight regions in d_ws (bf16), FC composed into gates ----
// B-frag layout: [ntile][kstep][lane(64)][8]; n = nt*16+(lane&15), k = ks*32+(lane>>4)*8+e
// Gate K-space (R/Z): ks0-1 = [s(0..29)|a(30..35)|pad], ks2-8 = h
#define N_R9   (13*9*512)
#define N_NI   (13*2*512)
#define N_NH   (13*7*512)
#define N_W1   (13*7*512)
#define N_MV   (4*7*512)
#define OFF_R  0
#define OFF_Z  (OFF_R  + N_R9)
#define OFF_NI (OFF_Z  + N_R9)
#define OFF_NH (OFF_NI + N_NI)
#define OFF_W1 (OFF_NH + N_NH)
#define OFF_MV (OFF_W1 + N_W1)
#define W_TOTAL (OFF_MV + N_MV)    // 240640 elems = 481 KB

__device__ __forceinline__ unsigned short f2b(float f) {
    union { float f; unsigned u; } v; v.f = f;
    unsigned r = v.u + 0x7FFFu + ((v.u >> 16) & 1u);
    return (unsigned short)(r >> 16);
}
__device__ __forceinline__ float b2f(unsigned short h) {
    union { unsigned u; float f; } v; v.u = ((unsigned)h) << 16;
    return v.f;
}
__device__ __forceinline__ int fragSlot(int row, int k) {
    int sub = k & 31;
    return ((((sub >> 3) & 3) << 4) | row) * 8 + (sub & 7);
}
__device__ __forceinline__ f32x4 MFMA(bf16x8 a, bf16x8 b, f32x4 c) {
    return __builtin_amdgcn_mfma_f32_16x16x32_bf16(a, b, c, 0, 0, 0);
}
__device__ __forceinline__ float fast_rcp(float x) { return __builtin_amdgcn_rcpf(x); }
__device__ __forceinline__ float sigmf(float x) {
    return fast_rcp(1.f + __expf(-x));
}
__device__ __forceinline__ float tanh_fast(float x) {
    float e = __expf(2.f * fminf(x, 40.f));
    return (e - 1.f) * fast_rcp(e + 1.f);
}
__device__ __forceinline__ void st_nt4(float* p, f32x4 v) {
    __builtin_nontemporal_store(v, reinterpret_cast<f32x4*>(p));
}
__device__ __forceinline__ float ld_nt(const float* p) { return __builtin_nontemporal_load(p); }

// ================= weight prep: compose FC into gates, fp32 -> bf16, fragment-ordered =================
__global__ void rssm_prep(const float* __restrict__ Wfc, const float* __restrict__ Wih,
                          const float* __restrict__ Whh, const float* __restrict__ W1,
                          const float* __restrict__ Wmu, const float* __restrict__ Wvar,
                          unsigned short* __restrict__ out)
{
    int idx = blockIdx.x * 256 + threadIdx.x;
    if (idx >= W_TOTAL) return;
    float v = 0.f;
    if (idx < OFF_NI) {                       // R (idx<OFF_Z) or Z gate: [13][9][512]
        const int base = (idx < OFF_Z) ? OFF_R : OFF_Z;
        const int grow = (idx < OFF_Z) ? 0 : 200;
        int loc = idx - base;
        int nt = loc / (9 * 512), r = loc % (9 * 512), ks = r / 512, li = r % 512;
        int lane = li >> 3, e = li & 7;
        int n = nt * 16 + (lane & 15);
        int k = ks * 32 + (lane >> 4) * 8 + e;
        if (n < 200) {
            if (k < 36) {                      // composed (W_ih,g . W_fc)[n,k]
                float acc = 0.f;
                for (int m = 0; m < 200; ++m)
                    acc += Wih[(grow + n) * 200 + m] * Wfc[m * 36 + k];
                v = acc;
            } else if (k >= 64 && (k - 64) < 200) {
                v = Whh[(grow + n) * 200 + (k - 64)];
            }
        }
    } else if (idx < OFF_NH) {                // NI composed [13][2][512]
        int loc = idx - OFF_NI;
        int nt = loc / (2 * 512), r = loc % (2 * 512), ks = r / 512, li = r % 512;
        int lane = li >> 3, e = li & 7;
        int n = nt * 16 + (lane & 15);
        int k = ks * 32 + (lane >> 4) * 8 + e;
        if (n < 200 && k < 36) {
            float acc = 0.f;
            for (int m = 0; m < 200; ++m)
                acc += Wih[(400 + n) * 200 + m] * Wfc[m * 36 + k];
            v = acc;
        }
    } else if (idx < OFF_W1) {                // NH [13][7][512]
        int loc = idx - OFF_NH;
        int nt = loc / (7 * 512), r = loc % (7 * 512), ks = r / 512, li = r % 512;
        int lane = li >> 3, e = li & 7;
        int n = nt * 16 + (lane & 15);
        int k = ks * 32 + (lane >> 4) * 8 + e;
        if (n < 200 && k < 200) v = Whh[(400 + n) * 200 + k];
    } else if (idx < OFF_MV) {                // W1 [13][7][512]
        int loc = idx - OFF_W1;
        int nt = loc / (7 * 512), r = loc % (7 * 512), ks = r / 512, li = r % 512;
        int lane = li >> 3, e = li & 7;
        int n = nt * 16 + (lane & 15);
        int k = ks * 32 + (lane >> 4) * 8 + e;
        if (n < 200 && k < 200) v = W1[n * 200 + k];
    } else {                                  // MV [4][7][512]
        int loc = idx - OFF_MV;
        int nt = loc / (7 * 512), r = loc % (7 * 512), ks = r / 512, li = r % 512;
        int lane = li >> 3, e = li & 7;
        int k = ks * 32 + (lane >> 4) * 8 + e;
        if (nt < 2) { int m = nt * 16 + (lane & 15); if (m < 30 && k < 200) v = Wmu[m * 200 + k]; }
        else        { int m = (nt - 2) * 16 + (lane & 15); if (m < 30 && k < 200) v = Wvar[m * 200 + k]; }
    }
    out[idx] = f2b(v);
}

// ================= composed biases: CB[0..207]=R, [208..415]=Z, [416..623]=N_in =================
__global__ void rssm_bias(const float* __restrict__ Wih, const float* __restrict__ b_fc,
                          const float* __restrict__ b_ih, const float* __restrict__ b_hh,
                          float* __restrict__ cb)
{
    int j = blockIdx.x * 64 + threadIdx.x;
    if (j >= 624) return;
    int g = j / 208, n = j % 208;
    float v = 0.f;
    if (n < 200) {
        float acc = 0.f;
        for (int m = 0; m < 200; ++m)
            acc += Wih[(g * 200 + n) * 200 + m] * b_fc[m];
        if (g == 0)      v = acc + b_ih[n] + b_hh[n];
        else if (g == 1) v = acc + b_ih[200 + n] + b_hh[200 + n];
        else             v = acc + b_ih[400 + n];
    }
    cb[g * 208 + n] = v;
}

// ================= main kernel: 256 blocks x 32 rows, 8 waves; W1 LDS-resident; stores in phase A =================
__global__ __launch_bounds__(THREADS, 2) void rssm_main(
    const float* __restrict__ actions, const float* __restrict__ h0,
    const float* __restrict__ s0, const float* __restrict__ noise,
    const float* __restrict__ b_hh, const float* __restrict__ b1,
    const float* __restrict__ bmu, const float* __restrict__ bvar,
    const unsigned short* __restrict__ W, float* __restrict__ out)
{
    // Activation buffers, MFMA A-fragment layout [mt][ks][512] (mt in 0..1)
    __shared__ __align__(16) unsigned short Hb[2][2 * 7 * 512];     // h ping-pong  28672 B
    __shared__ __align__(16) unsigned short HIDb[2 * 7 * 512];      // hidden       14336 B
    __shared__ __align__(16) unsigned short SAb[2 * 2 * 512];       // s|a k0..35    4096 B
    __shared__ __align__(16) float STG_Z[ROWS * 30];                // stoch fp32    3840 B
    __shared__ __align__(16) float NZb[ROWS * 30];                  // noise stage   3840 B
    __shared__ __align__(16) unsigned short W1L[N_W1];              // W1 in LDS    93184 B
    // total 147968 B <= 163840

    const int tid = threadIdx.x;
    const int w = tid >> 6, lane = tid & 63;
    const int col = lane & 15, kg = lane >> 4;
    const int brow0 = blockIdx.x * ROWS;
    const int jt0 = w;
    const int jt1 = (w < 5) ? (w + 8) : -1;    // 13 tiles over 8 waves

    const unsigned short* WR  = W + OFF_R;
    const unsigned short* WZ  = W + OFF_Z;
    const unsigned short* WNI = W + OFF_NI;
    const unsigned short* WNH = W + OFF_NH;
    const unsigned short* W1w = W + OFF_W1;
    const unsigned short* WMV = W + OFF_MV;
    const float* CB = (const float*)(W + W_TOTAL);
    float* out_states = out;
    float* out_stoch  = out + (size_t)T_STEPS * BATCH * 200;

    // ---- hoisted per-jt biases ----
    float brv[2] = {0.f, 0.f}, bzv[2] = {0.f, 0.f}, biv[2] = {0.f, 0.f};
    float bhv[2] = {0.f, 0.f}, b1v[2] = {0.f, 0.f};
    #pragma unroll
    for (int ji = 0; ji < 2; ++ji) {
        const int jt = ji ? jt1 : jt0;
        if (jt < 0) continue;
        const int j = jt * 16 + col;
        if (j < 200) {
            brv[ji] = CB[j];
            bzv[ji] = CB[208 + j];
            biv[ji] = CB[416 + j];
            bhv[ji] = b_hh[400 + j];
            b1v[ji] = b1[j];
        }
    }
    float bmuv = 0.f, bvav = 0.f;
    if (w < 4) {
        const int jm = (w & 1) * 16 + col;
        if (jm < 30) { bmuv = bmu[jm]; bvav = bvar[jm]; }
    }

    // ---- init: zero LDS (pad slots must be 0), copy W1 to LDS, load h0/s0/a0 ----
    for (int i = tid; i < 2 * 7 * 512; i += THREADS) { Hb[0][i] = 0; Hb[1][i] = 0; }
    for (int i = tid; i < 2 * 7 * 512; i += THREADS) HIDb[i] = 0;
    for (int i = tid; i < 2 * 2 * 512; i += THREADS) SAb[i] = 0;
    {
        const u32x4* s1 = reinterpret_cast<const u32x4*>(W1w);
        u32x4* d1 = reinterpret_cast<u32x4*>(W1L);
        for (int i = tid; i < N_W1 / 8; i += THREADS) d1[i] = s1[i];
    }
    __syncthreads();
    for (int i = tid; i < ROWS * 200; i += THREADS) {
        int r = i / 200, jj = i % 200;
        Hb[0][((r >> 4) * 7 + (jj >> 5)) * 512 + fragSlot(r & 15, jj)] =
            f2b(h0[(size_t)(brow0 + r) * 200 + jj]);
    }
    for (int i = tid; i < ROWS * 30; i += THREADS) {
        int r = i / 30, jj = i % 30;
        SAb[((r >> 4) * 2) * 512 + fragSlot(r & 15, jj)] =
            f2b(s0[(size_t)(brow0 + r) * 30 + jj]);
    }
    for (int i = tid; i < ROWS * 6; i += THREADS) {
        int r = i / 6, c = i % 6, k = 30 + c;
        SAb[((r >> 4) * 2 + (k >> 5)) * 512 + fragSlot(r & 15, k)] =
            f2b(ld_nt(&actions[(size_t)(brow0 + r) * 6 + c]));
    }
    __syncthreads();

    for (int t = 0; t < T_STEPS; ++t) {
        const int cur = t & 1, nxt = cur ^ 1;

        // ---------- Phase A ----------
        // waves 5-7 (single-tile): issue ALL global stores first so they retire
        // under phase A's long compute (stoch(t-1) + states(t-1) from Hb[cur]),
        // plus stage noise(t) -> LDS.
        if (jt1 < 0) {
            const int idx = (w - 5) * 64 + lane;   // 0..191
            if (t >= 1) {
                float* dstz = out_stoch + ((size_t)(t - 1) * BATCH + brow0) * 30;
                for (int i = idx; i < 240; i += 192) {
                    f32x4 v = *reinterpret_cast<const f32x4*>(&STG_Z[i * 4]);
                    st_nt4(dstz + i * 4, v);
                }
                // states(t-1) lives in Hb[cur] (fragment layout), stable during phase A
                float* dsts = out_states + ((size_t)(t - 1) * BATCH + brow0) * 200;
                for (int i = idx; i < 1600; i += 192) {
                    const int e0 = i * 4;
                    const int r = e0 / 200, j0 = e0 % 200;       // j0 % 4 == 0
                    const int mt = r >> 4, rr = r & 15;
                    u16x4 hv4 = *reinterpret_cast<const u16x4*>(
                        &Hb[cur][(mt * 7 + (j0 >> 5)) * 512 + fragSlot(rr, j0)]);
                    f32x4 v;
                    v[0] = b2f(hv4[0]); v[1] = b2f(hv4[1]);
                    v[2] = b2f(hv4[2]); v[3] = b2f(hv4[3]);
                    st_nt4(dsts + e0, v);
                }
            }
            const float* np = noise + ((size_t)t * BATCH + brow0) * 30;
            for (int i = idx; i < ROWS * 30; i += 192)
                NZb[i] = ld_nt(&np[i]);
        }
        // gates over K=[s|a|pad|h]; h_new -> Hb[nxt]
        #pragma unroll
        for (int ji = 0; ji < 2; ++ji) {
            const int jt = ji ? jt1 : jt0;
            if (jt < 0) continue;
            // prefetch this tile's 27 weight frags (from L2)
            bf16x8 wRr[9], wZr[9], wNi[2], wNh[7];
            #pragma unroll
            for (int ks = 0; ks < 9; ++ks) {
                wRr[ks] = *reinterpret_cast<const bf16x8*>(&WR[(size_t)(jt * 9 + ks) * 512 + lane * 8]);
                wZr[ks] = *reinterpret_cast<const bf16x8*>(&WZ[(size_t)(jt * 9 + ks) * 512 + lane * 8]);
            }
            #pragma unroll
            for (int ks = 0; ks < 2; ++ks)
                wNi[ks] = *reinterpret_cast<const bf16x8*>(&WNI[(size_t)(jt * 2 + ks) * 512 + lane * 8]);
            #pragma unroll
            for (int ks = 0; ks < 7; ++ks)
                wNh[ks] = *reinterpret_cast<const bf16x8*>(&WNH[(size_t)(jt * 7 + ks) * 512 + lane * 8]);

            // accumulators seeded with composed biases
            f32x4 aR[2], aZ[2], aNi[2], aNh[2];
            #pragma unroll
            for (int mt = 0; mt < 2; ++mt) {
                aR[mt]  = (f32x4){brv[ji], brv[ji], brv[ji], brv[ji]};
                aZ[mt]  = (f32x4){bzv[ji], bzv[ji], bzv[ji], bzv[ji]};
                aNi[mt] = (f32x4){biv[ji], biv[ji], biv[ji], biv[ji]};
                aNh[mt] = (f32x4){bhv[ji], bhv[ji], bhv[ji], bhv[ji]};
            }
            __builtin_amdgcn_s_setprio(1);
            #pragma unroll
            for (int ks = 0; ks < 9; ++ks) {
                #pragma unroll
                for (int mt = 0; mt < 2; ++mt) {
                    bf16x8 a = (ks < 2)
                        ? *reinterpret_cast<const bf16x8*>(&SAb[(mt * 2 + ks) * 512 + lane * 8])
                        : *reinterpret_cast<const bf16x8*>(&Hb[cur][(mt * 7 + (ks - 2)) * 512 + lane * 8]);
                    aR[mt] = MFMA(a, wRr[ks], aR[mt]);
                    aZ[mt] = MFMA(a, wZr[ks], aZ[mt]);
                    if (ks < 2) aNi[mt] = MFMA(a, wNi[ks], aNi[mt]);
                    else        aNh[mt] = MFMA(a, wNh[ks - 2], aNh[mt]);
                }
            }
            __builtin_amdgcn_s_setprio(0);
            // elementwise + h_new
            const int j = jt * 16 + col;
            const bool jv = (j < 200);
            #pragma unroll
            for (int mt = 0; mt < 2; ++mt) {
                #pragma unroll
                for (int q = 0; q < 4; ++q) {
                    const int r0 = kg * 4 + q;
                    const int slot = (j >> 5) * 512 + fragSlot(r0, j);
                    float rg = sigmf(aR[mt][q]);
                    float zg = sigmf(aZ[mt][q]);
                    float ng = tanh_fast(aNi[mt][q] + rg * aNh[mt][q]);
                    if (jv) {
                        float hv = b2f(Hb[cur][mt * 7 * 512 + slot]);
                        float hn = ng + zg * (hv - ng);
                        Hb[nxt][mt * 7 * 512 + slot] = f2b(hn);
                    }
                }
            }
        }
        __syncthreads();

        // ---------- Phase B: hid = relu(h_new @ W1^T + b1) -> HIDb (weights from LDS) ----------
        // waves 0-3: prefetch MV weight frags NOW so their L2 latency hides under
        // phase B's MFMA work; they stay live across the B->C barrier.
        bf16x8 wm[7], wv[7];
        if (w < 4) {
            const int ntile = w & 1;
            #pragma unroll
            for (int ks = 0; ks < 7; ++ks) {
                wm[ks] = *reinterpret_cast<const bf16x8*>(&WMV[(size_t)(ntile * 7 + ks) * 512 + lane * 8]);
                wv[ks] = *reinterpret_cast<const bf16x8*>(&WMV[(size_t)((2 + ntile) * 7 + ks) * 512 + lane * 8]);
            }
        }
        #pragma unroll
        for (int ji = 0; ji < 2; ++ji) {
            const int jt = ji ? jt1 : jt0;
            if (jt < 0) continue;
            f32x4 c0 = {b1v[ji], b1v[ji], b1v[ji], b1v[ji]};
            f32x4 c1 = {b1v[ji], b1v[ji], b1v[ji], b1v[ji]};
            #pragma unroll
            for (int ks = 0; ks < 7; ++ks) {
                bf16x8 wbv = *reinterpret_cast<const bf16x8*>(&W1L[(size_t)(jt * 7 + ks) * 512 + lane * 8]);
                bf16x8 a0 = *reinterpret_cast<const bf16x8*>(&Hb[nxt][(0 * 7 + ks) * 512 + lane * 8]);
                bf16x8 a1 = *reinterpret_cast<const bf16x8*>(&Hb[nxt][(1 * 7 + ks) * 512 + lane * 8]);
                c0 = MFMA(a0, wbv, c0);
                c1 = MFMA(a1, wbv, c1);
            }
            const int j = jt * 16 + col;
            #pragma unroll
            for (int q = 0; q < 4; ++q) {
                HIDb[(0 * 7 + (j >> 5)) * 512 + fragSlot(kg * 4 + q, j)] = f2b(fmaxf(c0[q], 0.f));
                HIDb[(1 * 7 + (j >> 5)) * 512 + fragSlot(kg * 4 + q, j)] = f2b(fmaxf(c1[q], 0.f));
            }
        }
        __syncthreads();

        // ---------- Phase C: waves 0-3 mu/var -> s_new (weights prefetched) ; waves 4-7 prefetch actions ----------
        if (w < 4) {
            const int mt = w >> 1;
            f32x4 cm = {bmuv, bmuv, bmuv, bmuv};
            f32x4 cv = {bvav, bvav, bvav, bvav};
            #pragma unroll
            for (int ks = 0; ks < 7; ++ks) {
                bf16x8 a = *reinterpret_cast<const bf16x8*>(&HIDb[(mt * 7 + ks) * 512 + lane * 8]);
                cm = MFMA(a, wm[ks], cm);
                cv = MFMA(a, wv[ks], cv);
            }
            const int jm = (w & 1) * 16 + col;
            const bool jmv = (jm < 30);
            #pragma unroll
            for (int q = 0; q < 4; ++q) {
                const int r0 = kg * 4 + q;
                const int row = mt * 16 + r0;
                float mu = cm[q];
                float vr = cv[q];
                float var = ((vr > 20.f) ? vr : log1pf(__expf(vr))) + 0.1f;
                if (jmv) {
                    float eps = NZb[row * 30 + jm];
                    float sn = mu + var * eps;
                    STG_Z[row * 30 + jm] = sn;
                    SAb[(mt * 2) * 512 + fragSlot(r0, jm)] = f2b(sn);
                }
            }
        } else {
            const int di = (w - 4) * 64 + lane;   // 0..255
            // prefetch actions(t+1) only — no global stores near this barrier
            if (t + 1 < T_STEPS && di < ROWS * 6) {
                const int r = di / 6, c = di % 6, k = 30 + c;
                float av = ld_nt(&actions[((size_t)(t + 1) * BATCH + brow0 + r) * 6 + c]);
                SAb[((r >> 4) * 2 + (k >> 5)) * 512 + fragSlot(r & 15, k)] = f2b(av);
            }
        }
        __syncthreads();
    }

    // ---- tail: drain states(T-1) from Hb[T_STEPS & 1] and stoch(T-1) ----
    {
        const int fin = T_STEPS & 1;   // buffer holding h_new of step T-1
        float* dsts = out_states + ((size_t)(T_STEPS - 1) * BATCH + brow0) * 200;
        for (int i = tid; i < 1600; i += THREADS) {
            const int e0 = i * 4;
            const int r = e0 / 200, j0 = e0 % 200;
            const int mt = r >> 4, rr = r & 15;
            u16x4 hv4 = *reinterpret_cast<const u16x4*>(
                &Hb[fin][(mt * 7 + (j0 >> 5)) * 512 + fragSlot(rr, j0)]);
            f32x4 v;
            v[0] = b2f(hv4[0]); v[1] = b2f(hv4[1]);
            v[2] = b2f(hv4[2]); v[3] = b2f(hv4[3]);
            st_nt4(dsts + e0, v);
        }
        if (tid < 240) {
            f32x4 v = *reinterpret_cast<const f32x4*>(&STG_Z[tid * 4]);
            st_nt4(out_stoch + ((size_t)(T_STEPS - 1) * BATCH + brow0) * 30 + tid * 4, v);
        }
    }
}

extern "C" void kernel_launch(void* const* d_in, const int* in_sizes, int n_in,
                              void* d_out, int out_size, void* d_ws, size_t ws_size,
                              hipStream_t stream)
{
    const float* actions = (const float*)d_in[0];
    const float* h0      = (const float*)d_in[1];
    const float* s0      = (const float*)d_in[2];
    const float* noise   = (const float*)d_in[3];
    const float* Wfc     = (const float*)d_in[4];
    const float* bfc     = (const float*)d_in[5];
    const float* Wih     = (const float*)d_in[6];
    const float* bih     = (const float*)d_in[7];
    const float* Whh     = (const float*)d_in[8];
    const float* bhh     = (const float*)d_in[9];
    const float* W1      = (const float*)d_in[10];
    const float* b1      = (const float*)d_in[11];
    const float* Wmu     = (const float*)d_in[12];
    const float* bmu     = (const float*)d_in[13];
    const float* Wvar    = (const float*)d_in[14];
    const float* bvar    = (const float*)d_in[15];

    unsigned short* wbuf = (unsigned short*)d_ws;
    float* cb = (float*)(wbuf + W_TOTAL);

    rssm_prep<<<(W_TOTAL + 255) / 256, 256, 0, stream>>>(Wfc, Wih, Whh, W1, Wmu, Wvar, wbuf);
    rssm_bias<<<10, 64, 0, stream>>>(Wih, bfc, bih, bhh, cb);
    rssm_main<<<NBLK, THREADS, 0, stream>>>(actions, h0, s0, noise, bhh, b1,
                                            bmu, bvar, wbuf, (float*)d_out);
}

// Round 19
// 1157.804 us; speedup vs baseline: 1.2909x; 1.2909x over previous
//
#include <hip/hip_runtime.h>
#include <hip/hip_bf16.h>
#include <cmath>

#define T_STEPS 50
#define BATCH   8192
#define ROWS    32                 // rows per block
#define NBLK    (BATCH / ROWS)     // 256 blocks
#define THREADS 512                // 8 waves

typedef float  f32x4  __attribute__((ext_vector_type(4)));
typedef __bf16 bf16x8 __attribute__((ext_vector_type(8)));
typedef unsigned int u32x4 __attribute__((ext_vector_type(4)));
typedef unsigned short u16x4 __attribute__((ext_vector_type(4)));

// ---- packed weight regions in d_ws (bf16), FC composed into gates ----
// B-frag layout: [ntile][kstep][lane(64)][8]; n = nt*16+(lane&15), k = ks*32+(lane>>4)*8+e
// Gate K-space (R/Z): ks0-1 = [s(0..29)|a(30..35)|pad], ks2-8 = h
#define N_R9   (13*9*512)
#define N_NI   (13*2*512)
#define N_NH   (13*7*512)
#define N_W1   (13*7*512)
#define N_MV   (4*7*512)
#define OFF_R  0
#define OFF_Z  (OFF_R  + N_R9)
#define OFF_NI (OFF_Z  + N_R9)
#define OFF_NH (OFF_NI + N_NI)
#define OFF_W1 (OFF_NH + N_NH)
#define OFF_MV (OFF_W1 + N_W1)
#define W_TOTAL (OFF_MV + N_MV)    // 240640 elems = 481 KB

__device__ __forceinline__ unsigned short f2b(float f) {
    union { float f; unsigned u; } v; v.f = f;
    unsigned r = v.u + 0x7FFFu + ((v.u >> 16) & 1u);
    return (unsigned short)(r >> 16);
}
__device__ __forceinline__ float b2f(unsigned short h) {
    union { unsigned u; float f; } v; v.u = ((unsigned)h) << 16;
    return v.f;
}
__device__ __forceinline__ int fragSlot(int row, int k) {
    int sub = k & 31;
    return ((((sub >> 3) & 3) << 4) | row) * 8 + (sub & 7);
}
__device__ __forceinline__ f32x4 MFMA(bf16x8 a, bf16x8 b, f32x4 c) {
    return __builtin_amdgcn_mfma_f32_16x16x32_bf16(a, b, c, 0, 0, 0);
}
__device__ __forceinline__ float fast_rcp(float x) { return __builtin_amdgcn_rcpf(x); }
__device__ __forceinline__ float sigmf(float x) {
    return fast_rcp(1.f + __expf(-x));
}
__device__ __forceinline__ float tanh_fast(float x) {
    float e = __expf(2.f * fminf(x, 40.f));
    return (e - 1.f) * fast_rcp(e + 1.f);
}
__device__ __forceinline__ void st_nt4(float* p, f32x4 v) {
    __builtin_nontemporal_store(v, reinterpret_cast<f32x4*>(p));
}
__device__ __forceinline__ float ld_nt(const float* p) { return __builtin_nontemporal_load(p); }

// ================= weight prep: compose FC into gates, fp32 -> bf16, fragment-ordered =================
__global__ void rssm_prep(const float* __restrict__ Wfc, const float* __restrict__ Wih,
                          const float* __restrict__ Whh, const float* __restrict__ W1,
                          const float* __restrict__ Wmu, const float* __restrict__ Wvar,
                          unsigned short* __restrict__ out)
{
    int idx = blockIdx.x * 256 + threadIdx.x;
    if (idx >= W_TOTAL) return;
    float v = 0.f;
    if (idx < OFF_NI) {                       // R (idx<OFF_Z) or Z gate: [13][9][512]
        const int base = (idx < OFF_Z) ? OFF_R : OFF_Z;
        const int grow = (idx < OFF_Z) ? 0 : 200;
        int loc = idx - base;
        int nt = loc / (9 * 512), r = loc % (9 * 512), ks = r / 512, li = r % 512;
        int lane = li >> 3, e = li & 7;
        int n = nt * 16 + (lane & 15);
        int k = ks * 32 + (lane >> 4) * 8 + e;
        if (n < 200) {
            if (k < 36) {                      // composed (W_ih,g . W_fc)[n,k]
                float acc = 0.f;
                for (int m = 0; m < 200; ++m)
                    acc += Wih[(grow + n) * 200 + m] * Wfc[m * 36 + k];
                v = acc;
            } else if (k >= 64 && (k - 64) < 200) {
                v = Whh[(grow + n) * 200 + (k - 64)];
            }
        }
    } else if (idx < OFF_NH) {                // NI composed [13][2][512]
        int loc = idx - OFF_NI;
        int nt = loc / (2 * 512), r = loc % (2 * 512), ks = r / 512, li = r % 512;
        int lane = li >> 3, e = li & 7;
        int n = nt * 16 + (lane & 15);
        int k = ks * 32 + (lane >> 4) * 8 + e;
        if (n < 200 && k < 36) {
            float acc = 0.f;
            for (int m = 0; m < 200; ++m)
                acc += Wih[(400 + n) * 200 + m] * Wfc[m * 36 + k];
            v = acc;
        }
    } else if (idx < OFF_W1) {                // NH [13][7][512]
        int loc = idx - OFF_NH;
        int nt = loc / (7 * 512), r = loc % (7 * 512), ks = r / 512, li = r % 512;
        int lane = li >> 3, e = li & 7;
        int n = nt * 16 + (lane & 15);
        int k = ks * 32 + (lane >> 4) * 8 + e;
        if (n < 200 && k < 200) v = Whh[(400 + n) * 200 + k];
    } else if (idx < OFF_MV) {                // W1 [13][7][512]
        int loc = idx - OFF_W1;
        int nt = loc / (7 * 512), r = loc % (7 * 512), ks = r / 512, li = r % 512;
        int lane = li >> 3, e = li & 7;
        int n = nt * 16 + (lane & 15);
        int k = ks * 32 + (lane >> 4) * 8 + e;
        if (n < 200 && k < 200) v = W1[n * 200 + k];
    } else {                                  // MV [4][7][512]
        int loc = idx - OFF_MV;
        int nt = loc / (7 * 512), r = loc % (7 * 512), ks = r / 512, li = r % 512;
        int lane = li >> 3, e = li & 7;
        int k = ks * 32 + (lane >> 4) * 8 + e;
        if (nt < 2) { int m = nt * 16 + (lane & 15); if (m < 30 && k < 200) v = Wmu[m * 200 + k]; }
        else        { int m = (nt - 2) * 16 + (lane & 15); if (m < 30 && k < 200) v = Wvar[m * 200 + k]; }
    }
    out[idx] = f2b(v);
}

// ================= composed biases: CB[0..207]=R, [208..415]=Z, [416..623]=N_in =================
__global__ void rssm_bias(const float* __restrict__ Wih, const float* __restrict__ b_fc,
                          const float* __restrict__ b_ih, const float* __restrict__ b_hh,
                          float* __restrict__ cb)
{
    int j = blockIdx.x * 64 + threadIdx.x;
    if (j >= 624) return;
    int g = j / 208, n = j % 208;
    float v = 0.f;
    if (n < 200) {
        float acc = 0.f;
        for (int m = 0; m < 200; ++m)
            acc += Wih[(g * 200 + n) * 200 + m] * b_fc[m];
        if (g == 0)      v = acc + b_ih[n] + b_hh[n];
        else if (g == 1) v = acc + b_ih[200 + n] + b_hh[200 + n];
        else             v = acc + b_ih[400 + n];
    }
    cb[g * 208 + n] = v;
}

// ================= main kernel: 256 blocks x 32 rows, 8 waves; W1 LDS-resident; stores in phase A =================
__global__ __launch_bounds__(THREADS, 2) void rssm_main(
    const float* __restrict__ actions, const float* __restrict__ h0,
    const float* __restrict__ s0, const float* __restrict__ noise,
    const float* __restrict__ b_hh, const float* __restrict__ b1,
    const float* __restrict__ bmu, const float* __restrict__ bvar,
    const unsigned short* __restrict__ W, float* __restrict__ out)
{
    // Activation buffers, MFMA A-fragment layout [mt][ks][512] (mt in 0..1)
    __shared__ __align__(16) unsigned short Hb[2][2 * 7 * 512];     // h ping-pong  28672 B
    __shared__ __align__(16) unsigned short HIDb[2 * 7 * 512];      // hidden       14336 B
    __shared__ __align__(16) unsigned short SAb[2 * 2 * 512];       // s|a k0..35    4096 B
    __shared__ __align__(16) float STG_Z[ROWS * 30];                // stoch fp32    3840 B
    __shared__ __align__(16) float NZb[ROWS * 30];                  // noise stage   3840 B
    __shared__ __align__(16) unsigned short W1L[N_W1];              // W1 in LDS    93184 B
    // total 147968 B <= 163840

    const int tid = threadIdx.x;
    const int w = tid >> 6, lane = tid & 63;
    const int col = lane & 15, kg = lane >> 4;
    const int brow0 = blockIdx.x * ROWS;
    const int jt0 = w;
    const int jt1 = (w < 5) ? (w + 8) : -1;    // 13 tiles over 8 waves

    const unsigned short* WR  = W + OFF_R;
    const unsigned short* WZ  = W + OFF_Z;
    const unsigned short* WNI = W + OFF_NI;
    const unsigned short* WNH = W + OFF_NH;
    const unsigned short* W1w = W + OFF_W1;
    const unsigned short* WMV = W + OFF_MV;
    const float* CB = (const float*)(W + W_TOTAL);
    float* out_states = out;
    float* out_stoch  = out + (size_t)T_STEPS * BATCH * 200;

    // ---- hoisted per-jt biases ----
    float brv[2] = {0.f, 0.f}, bzv[2] = {0.f, 0.f}, biv[2] = {0.f, 0.f};
    float bhv[2] = {0.f, 0.f}, b1v[2] = {0.f, 0.f};
    #pragma unroll
    for (int ji = 0; ji < 2; ++ji) {
        const int jt = ji ? jt1 : jt0;
        if (jt < 0) continue;
        const int j = jt * 16 + col;
        if (j < 200) {
            brv[ji] = CB[j];
            bzv[ji] = CB[208 + j];
            biv[ji] = CB[416 + j];
            bhv[ji] = b_hh[400 + j];
            b1v[ji] = b1[j];
        }
    }
    float bmuv = 0.f, bvav = 0.f;
    if (w < 4) {
        const int jm = (w & 1) * 16 + col;
        if (jm < 30) { bmuv = bmu[jm]; bvav = bvar[jm]; }
    }

    // ---- init: zero LDS (pad slots must be 0), copy W1 to LDS, load h0/s0/a0 ----
    for (int i = tid; i < 2 * 7 * 512; i += THREADS) { Hb[0][i] = 0; Hb[1][i] = 0; }
    for (int i = tid; i < 2 * 7 * 512; i += THREADS) HIDb[i] = 0;
    for (int i = tid; i < 2 * 2 * 512; i += THREADS) SAb[i] = 0;
    {
        const u32x4* s1 = reinterpret_cast<const u32x4*>(W1w);
        u32x4* d1 = reinterpret_cast<u32x4*>(W1L);
        for (int i = tid; i < N_W1 / 8; i += THREADS) d1[i] = s1[i];
    }
    __syncthreads();
    for (int i = tid; i < ROWS * 200; i += THREADS) {
        int r = i / 200, jj = i % 200;
        Hb[0][((r >> 4) * 7 + (jj >> 5)) * 512 + fragSlot(r & 15, jj)] =
            f2b(h0[(size_t)(brow0 + r) * 200 + jj]);
    }
    for (int i = tid; i < ROWS * 30; i += THREADS) {
        int r = i / 30, jj = i % 30;
        SAb[((r >> 4) * 2) * 512 + fragSlot(r & 15, jj)] =
            f2b(s0[(size_t)(brow0 + r) * 30 + jj]);
    }
    for (int i = tid; i < ROWS * 6; i += THREADS) {
        int r = i / 6, c = i % 6, k = 30 + c;
        SAb[((r >> 4) * 2 + (k >> 5)) * 512 + fragSlot(r & 15, k)] =
            f2b(ld_nt(&actions[(size_t)(brow0 + r) * 6 + c]));
    }
    __syncthreads();

    for (int t = 0; t < T_STEPS; ++t) {
        const int cur = t & 1, nxt = cur ^ 1;

        // ---------- Phase A ----------
        // waves 5-7 (single-tile): issue ALL global stores first so they retire
        // under phase A's long compute (stoch(t-1) + states(t-1) from Hb[cur]),
        // plus stage noise(t) -> LDS.
        if (jt1 < 0) {
            const int idx = (w - 5) * 64 + lane;   // 0..191
            if (t >= 1) {
                float* dstz = out_stoch + ((size_t)(t - 1) * BATCH + brow0) * 30;
                for (int i = idx; i < 240; i += 192) {
                    f32x4 v = *reinterpret_cast<const f32x4*>(&STG_Z[i * 4]);
                    st_nt4(dstz + i * 4, v);
                }
                // states(t-1) lives in Hb[cur] (fragment layout), stable during phase A
                float* dsts = out_states + ((size_t)(t - 1) * BATCH + brow0) * 200;
                for (int i = idx; i < 1600; i += 192) {
                    const int e0 = i * 4;
                    const int r = e0 / 200, j0 = e0 % 200;       // j0 % 4 == 0
                    const int mt = r >> 4, rr = r & 15;
                    u16x4 hv4 = *reinterpret_cast<const u16x4*>(
                        &Hb[cur][(mt * 7 + (j0 >> 5)) * 512 + fragSlot(rr, j0)]);
                    f32x4 v;
                    v[0] = b2f(hv4[0]); v[1] = b2f(hv4[1]);
                    v[2] = b2f(hv4[2]); v[3] = b2f(hv4[3]);
                    st_nt4(dsts + e0, v);
                }
            }
            const float* np = noise + ((size_t)t * BATCH + brow0) * 30;
            for (int i = idx; i < ROWS * 30; i += 192)
                NZb[i] = ld_nt(&np[i]);
        }
        // gates over K=[s|a|pad|h]; h_new -> Hb[nxt]
        #pragma unroll
        for (int ji = 0; ji < 2; ++ji) {
            const int jt = ji ? jt1 : jt0;
            if (jt < 0) continue;
            // prefetch this tile's 27 weight frags (from L2)
            bf16x8 wRr[9], wZr[9], wNi[2], wNh[7];
            #pragma unroll
            for (int ks = 0; ks < 9; ++ks) {
                wRr[ks] = *reinterpret_cast<const bf16x8*>(&WR[(size_t)(jt * 9 + ks) * 512 + lane * 8]);
                wZr[ks] = *reinterpret_cast<const bf16x8*>(&WZ[(size_t)(jt * 9 + ks) * 512 + lane * 8]);
            }
            #pragma unroll
            for (int ks = 0; ks < 2; ++ks)
                wNi[ks] = *reinterpret_cast<const bf16x8*>(&WNI[(size_t)(jt * 2 + ks) * 512 + lane * 8]);
            #pragma unroll
            for (int ks = 0; ks < 7; ++ks)
                wNh[ks] = *reinterpret_cast<const bf16x8*>(&WNH[(size_t)(jt * 7 + ks) * 512 + lane * 8]);

            // accumulators seeded with composed biases
            f32x4 aR[2], aZ[2], aNi[2], aNh[2];
            #pragma unroll
            for (int mt = 0; mt < 2; ++mt) {
                aR[mt]  = (f32x4){brv[ji], brv[ji], brv[ji], brv[ji]};
                aZ[mt]  = (f32x4){bzv[ji], bzv[ji], bzv[ji], bzv[ji]};
                aNi[mt] = (f32x4){biv[ji], biv[ji], biv[ji], biv[ji]};
                aNh[mt] = (f32x4){bhv[ji], bhv[ji], bhv[ji], bhv[ji]};
            }
            __builtin_amdgcn_s_setprio(1);
            #pragma unroll
            for (int ks = 0; ks < 9; ++ks) {
                #pragma unroll
                for (int mt = 0; mt < 2; ++mt) {
                    bf16x8 a = (ks < 2)
                        ? *reinterpret_cast<const bf16x8*>(&SAb[(mt * 2 + ks) * 512 + lane * 8])
                        : *reinterpret_cast<const bf16x8*>(&Hb[cur][(mt * 7 + (ks - 2)) * 512 + lane * 8]);
                    aR[mt] = MFMA(a, wRr[ks], aR[mt]);
                    aZ[mt] = MFMA(a, wZr[ks], aZ[mt]);
                    if (ks < 2) aNi[mt] = MFMA(a, wNi[ks], aNi[mt]);
                    else        aNh[mt] = MFMA(a, wNh[ks - 2], aNh[mt]);
                }
            }
            __builtin_amdgcn_s_setprio(0);
            // elementwise + h_new
            const int j = jt * 16 + col;
            const bool jv = (j < 200);
            #pragma unroll
            for (int mt = 0; mt < 2; ++mt) {
                #pragma unroll
                for (int q = 0; q < 4; ++q) {
                    const int r0 = kg * 4 + q;
                    const int slot = (j >> 5) * 512 + fragSlot(r0, j);
                    float rg = sigmf(aR[mt][q]);
                    float zg = sigmf(aZ[mt][q]);
                    float ng = tanh_fast(aNi[mt][q] + rg * aNh[mt][q]);
                    if (jv) {
                        float hv = b2f(Hb[cur][mt * 7 * 512 + slot]);
                        float hn = ng + zg * (hv - ng);
                        Hb[nxt][mt * 7 * 512 + slot] = f2b(hn);
                    }
                }
            }
        }
        __syncthreads();

        // ---------- Phase B: hid = relu(h_new @ W1^T + b1) -> HIDb (weights from LDS) ----------
        #pragma unroll
        for (int ji = 0; ji < 2; ++ji) {
            const int jt = ji ? jt1 : jt0;
            if (jt < 0) continue;
            f32x4 c0 = {b1v[ji], b1v[ji], b1v[ji], b1v[ji]};
            f32x4 c1 = {b1v[ji], b1v[ji], b1v[ji], b1v[ji]};
            #pragma unroll
            for (int ks = 0; ks < 7; ++ks) {
                bf16x8 wbv = *reinterpret_cast<const bf16x8*>(&W1L[(size_t)(jt * 7 + ks) * 512 + lane * 8]);
                bf16x8 a0 = *reinterpret_cast<const bf16x8*>(&Hb[nxt][(0 * 7 + ks) * 512 + lane * 8]);
                bf16x8 a1 = *reinterpret_cast<const bf16x8*>(&Hb[nxt][(1 * 7 + ks) * 512 + lane * 8]);
                c0 = MFMA(a0, wbv, c0);
                c1 = MFMA(a1, wbv, c1);
            }
            const int j = jt * 16 + col;
            #pragma unroll
            for (int q = 0; q < 4; ++q) {
                HIDb[(0 * 7 + (j >> 5)) * 512 + fragSlot(kg * 4 + q, j)] = f2b(fmaxf(c0[q], 0.f));
                HIDb[(1 * 7 + (j >> 5)) * 512 + fragSlot(kg * 4 + q, j)] = f2b(fmaxf(c1[q], 0.f));
            }
        }
        __syncthreads();

        // ---------- Phase C: waves 0-3 mu/var -> s_new ; waves 4-7 prefetch actions ----------
        if (w < 4) {
            const int mt = w >> 1, ntile = w & 1;
            bf16x8 wm[7], wv[7];
            #pragma unroll
            for (int ks = 0; ks < 7; ++ks) {
                wm[ks] = *reinterpret_cast<const bf16x8*>(&WMV[(size_t)(ntile * 7 + ks) * 512 + lane * 8]);
                wv[ks] = *reinterpret_cast<const bf16x8*>(&WMV[(size_t)((2 + ntile) * 7 + ks) * 512 + lane * 8]);
            }
            f32x4 cm = {bmuv, bmuv, bmuv, bmuv};
            f32x4 cv = {bvav, bvav, bvav, bvav};
            #pragma unroll
            for (int ks = 0; ks < 7; ++ks) {
                bf16x8 a = *reinterpret_cast<const bf16x8*>(&HIDb[(mt * 7 + ks) * 512 + lane * 8]);
                cm = MFMA(a, wm[ks], cm);
                cv = MFMA(a, wv[ks], cv);
            }
            const int jm = ntile * 16 + col;
            const bool jmv = (jm < 30);
            #pragma unroll
            for (int q = 0; q < 4; ++q) {
                const int r0 = kg * 4 + q;
                const int row = mt * 16 + r0;
                float mu = cm[q];
                float vr = cv[q];
                float var = ((vr > 20.f) ? vr : log1pf(__expf(vr))) + 0.1f;
                if (jmv) {
                    float eps = NZb[row * 30 + jm];
                    float sn = mu + var * eps;
                    STG_Z[row * 30 + jm] = sn;
                    SAb[(mt * 2) * 512 + fragSlot(r0, jm)] = f2b(sn);
                }
            }
        } else {
            const int di = (w - 4) * 64 + lane;   // 0..255
            // prefetch actions(t+1) only — no global stores near this barrier
            if (t + 1 < T_STEPS && di < ROWS * 6) {
                const int r = di / 6, c = di % 6, k = 30 + c;
                float av = ld_nt(&actions[((size_t)(t + 1) * BATCH + brow0 + r) * 6 + c]);
                SAb[((r >> 4) * 2 + (k >> 5)) * 512 + fragSlot(r & 15, k)] = f2b(av);
            }
        }
        __syncthreads();
    }

    // ---- tail: drain states(T-1) from Hb[T_STEPS & 1] and stoch(T-1) ----
    {
        const int fin = T_STEPS & 1;   // buffer holding h_new of step T-1
        float* dsts = out_states + ((size_t)(T_STEPS - 1) * BATCH + brow0) * 200;
        for (int i = tid; i < 1600; i += THREADS) {
            const int e0 = i * 4;
            const int r = e0 / 200, j0 = e0 % 200;
            const int mt = r >> 4, rr = r & 15;
            u16x4 hv4 = *reinterpret_cast<const u16x4*>(
                &Hb[fin][(mt * 7 + (j0 >> 5)) * 512 + fragSlot(rr, j0)]);
            f32x4 v;
            v[0] = b2f(hv4[0]); v[1] = b2f(hv4[1]);
            v[2] = b2f(hv4[2]); v[3] = b2f(hv4[3]);
            st_nt4(dsts + e0, v);
        }
        if (tid < 240) {
            f32x4 v = *reinterpret_cast<const f32x4*>(&STG_Z[tid * 4]);
            st_nt4(out_stoch + ((size_t)(T_STEPS - 1) * BATCH + brow0) * 30 + tid * 4, v);
        }
    }
}

extern "C" void kernel_launch(void* const* d_in, const int* in_sizes, int n_in,
                              void* d_out, int out_size, void* d_ws, size_t ws_size,
                              hipStream_t stream)
{
    const float* actions = (const float*)d_in[0];
    const float* h0      = (const float*)d_in[1];
    const float* s0      = (const float*)d_in[2];
    const float* noise   = (const float*)d_in[3];
    const float* Wfc     = (const float*)d_in[4];
    const float* bfc     = (const float*)d_in[5];
    const float* Wih     = (const float*)d_in[6];
    const float* bih     = (const float*)d_in[7];
    const float* Whh     = (const float*)d_in[8];
    const float* bhh     = (const float*)d_in[9];
    const float* W1      = (const float*)d_in[10];
    const float* b1      = (const float*)d_in[11];
    const float* Wmu     = (const float*)d_in[12];
    const float* bmu     = (const float*)d_in[13];
    const float* Wvar    = (const float*)d_in[14];
    const float* bvar    = (const float*)d_in[15];

    unsigned short* wbuf = (unsigned short*)d_ws;
    float* cb = (float*)(wbuf + W_TOTAL);

    rssm_prep<<<(W_TOTAL + 255) / 256, 256, 0, stream>>>(Wfc, Wih, Whh, W1, Wmu, Wvar, wbuf);
    rssm_bias<<<10, 64, 0, stream>>>(Wih, bfc, bih, bhh, cb);
    rssm_main<<<NBLK, THREADS, 0, stream>>>(actions, h0, s0, noise, bhh, b1,
                                            bmu, bvar, wbuf, (float*)d_out);
}

// Round 20
// 675.957 us; speedup vs baseline: 2.2112x; 1.7128x over previous
//
#include <hip/hip_runtime.h>
#include <hip/hip_bf16.h>
#include <cmath>

#define T_STEPS 50
#define BATCH   8192
#define ROWS    32                 // rows per block
#define NBLK    (BATCH / ROWS)     // 256 blocks
#define THREADS 512                // 8 waves

typedef float  f32x4  __attribute__((ext_vector_type(4)));
typedef __bf16 bf16x8 __attribute__((ext_vector_type(8)));
typedef unsigned int u32x4 __attribute__((ext_vector_type(4)));
typedef unsigned short u16x4 __attribute__((ext_vector_type(4)));

// ---- packed weight regions in d_ws (bf16), FC composed into gates ----
// B-frag layout: [ntile][kstep][lane(64)][8]; n = nt*16+(lane&15), k = ks*32+(lane>>4)*8+e
// Gate K-space (R/Z): ks0-1 = [s(0..29)|a(30..35)|pad], ks2-8 = h
#define N_R9   (13*9*512)
#define N_NI   (13*2*512)
#define N_NH   (13*7*512)
#define N_W1   (13*7*512)
#define N_MV   (4*7*512)
#define OFF_R  0
#define OFF_Z  (OFF_R  + N_R9)
#define OFF_NI (OFF_Z  + N_R9)
#define OFF_NH (OFF_NI + N_NI)
#define OFF_W1 (OFF_NH + N_NH)
#define OFF_MV (OFF_W1 + N_W1)
#define W_TOTAL (OFF_MV + N_MV)    // 240640 elems = 481 KB

__device__ __forceinline__ unsigned short f2b(float f) {
    union { float f; unsigned u; } v; v.f = f;
    unsigned r = v.u + 0x7FFFu + ((v.u >> 16) & 1u);
    return (unsigned short)(r >> 16);
}
__device__ __forceinline__ float b2f(unsigned short h) {
    union { unsigned u; float f; } v; v.u = ((unsigned)h) << 16;
    return v.f;
}
__device__ __forceinline__ int fragSlot(int row, int k) {
    int sub = k & 31;
    return ((((sub >> 3) & 3) << 4) | row) * 8 + (sub & 7);
}
__device__ __forceinline__ f32x4 MFMA(bf16x8 a, bf16x8 b, f32x4 c) {
    return __builtin_amdgcn_mfma_f32_16x16x32_bf16(a, b, c, 0, 0, 0);
}
__device__ __forceinline__ float fast_rcp(float x) { return __builtin_amdgcn_rcpf(x); }
__device__ __forceinline__ float sigmf(float x) {
    return fast_rcp(1.f + __expf(-x));
}
__device__ __forceinline__ float tanh_fast(float x) {
    float e = __expf(2.f * fminf(x, 40.f));
    return (e - 1.f) * fast_rcp(e + 1.f);
}
__device__ __forceinline__ void st_nt4(float* p, f32x4 v) {
    __builtin_nontemporal_store(v, reinterpret_cast<f32x4*>(p));
}
__device__ __forceinline__ float ld_nt(const float* p) { return __builtin_nontemporal_load(p); }

// ================= weight prep: compose FC into gates, fp32 -> bf16, fragment-ordered =================
__global__ void rssm_prep(const float* __restrict__ Wfc, const float* __restrict__ Wih,
                          const float* __restrict__ Whh, const float* __restrict__ W1,
                          const float* __restrict__ Wmu, const float* __restrict__ Wvar,
                          unsigned short* __restrict__ out)
{
    int idx = blockIdx.x * 256 + threadIdx.x;
    if (idx >= W_TOTAL) return;
    float v = 0.f;
    if (idx < OFF_NI) {                       // R (idx<OFF_Z) or Z gate: [13][9][512]
        const int base = (idx < OFF_Z) ? OFF_R : OFF_Z;
        const int grow = (idx < OFF_Z) ? 0 : 200;
        int loc = idx - base;
        int nt = loc / (9 * 512), r = loc % (9 * 512), ks = r / 512, li = r % 512;
        int lane = li >> 3, e = li & 7;
        int n = nt * 16 + (lane & 15);
        int k = ks * 32 + (lane >> 4) * 8 + e;
        if (n < 200) {
            if (k < 36) {                      // composed (W_ih,g . W_fc)[n,k]
                float acc = 0.f;
                for (int m = 0; m < 200; ++m)
                    acc += Wih[(grow + n) * 200 + m] * Wfc[m * 36 + k];
                v = acc;
            } else if (k >= 64 && (k - 64) < 200) {
                v = Whh[(grow + n) * 200 + (k - 64)];
            }
        }
    } else if (idx < OFF_NH) {                // NI composed [13][2][512]
        int loc = idx - OFF_NI;
        int nt = loc / (2 * 512), r = loc % (2 * 512), ks = r / 512, li = r % 512;
        int lane = li >> 3, e = li & 7;
        int n = nt * 16 + (lane & 15);
        int k = ks * 32 + (lane >> 4) * 8 + e;
        if (n < 200 && k < 36) {
            float acc = 0.f;
            for (int m = 0; m < 200; ++m)
                acc += Wih[(400 + n) * 200 + m] * Wfc[m * 36 + k];
            v = acc;
        }
    } else if (idx < OFF_W1) {                // NH [13][7][512]
        int loc = idx - OFF_NH;
        int nt = loc / (7 * 512), r = loc % (7 * 512), ks = r / 512, li = r % 512;
        int lane = li >> 3, e = li & 7;
        int n = nt * 16 + (lane & 15);
        int k = ks * 32 + (lane >> 4) * 8 + e;
        if (n < 200 && k < 200) v = Whh[(400 + n) * 200 + k];
    } else if (idx < OFF_MV) {                // W1 [13][7][512]
        int loc = idx - OFF_W1;
        int nt = loc / (7 * 512), r = loc % (7 * 512), ks = r / 512, li = r % 512;
        int lane = li >> 3, e = li & 7;
        int n = nt * 16 + (lane & 15);
        int k = ks * 32 + (lane >> 4) * 8 + e;
        if (n < 200 && k < 200) v = W1[n * 200 + k];
    } else {                                  // MV [4][7][512]
        int loc = idx - OFF_MV;
        int nt = loc / (7 * 512), r = loc % (7 * 512), ks = r / 512, li = r % 512;
        int lane = li >> 3, e = li & 7;
        int k = ks * 32 + (lane >> 4) * 8 + e;
        if (nt < 2) { int m = nt * 16 + (lane & 15); if (m < 30 && k < 200) v = Wmu[m * 200 + k]; }
        else        { int m = (nt - 2) * 16 + (lane & 15); if (m < 30 && k < 200) v = Wvar[m * 200 + k]; }
    }
    out[idx] = f2b(v);
}

// ================= composed biases: CB[0..207]=R, [208..415]=Z, [416..623]=N_in =================
__global__ void rssm_bias(const float* __restrict__ Wih, const float* __restrict__ b_fc,
                          const float* __restrict__ b_ih, const float* __restrict__ b_hh,
                          float* __restrict__ cb)
{
    int j = blockIdx.x * 64 + threadIdx.x;
    if (j >= 624) return;
    int g = j / 208, n = j % 208;
    float v = 0.f;
    if (n < 200) {
        float acc = 0.f;
        for (int m = 0; m < 200; ++m)
            acc += Wih[(g * 200 + n) * 200 + m] * b_fc[m];
        if (g == 0)      v = acc + b_ih[n] + b_hh[n];
        else if (g == 1) v = acc + b_ih[200 + n] + b_hh[200 + n];
        else             v = acc + b_ih[400 + n];
    }
    cb[g * 208 + n] = v;
}

// ================= main kernel: 256 blocks x 32 rows, 8 waves; W1 LDS-resident; stores in phase A =================
__global__ __launch_bounds__(THREADS, 2) void rssm_main(
    const float* __restrict__ actions, const float* __restrict__ h0,
    const float* __restrict__ s0, const float* __restrict__ noise,
    const float* __restrict__ b_hh, const float* __restrict__ b1,
    const float* __restrict__ bmu, const float* __restrict__ bvar,
    const unsigned short* __restrict__ W, float* __restrict__ out)
{
    // Activation buffers, MFMA A-fragment layout [mt][ks][512] (mt in 0..1)
    __shared__ __align__(16) unsigned short Hb[2][2 * 7 * 512];     // h ping-pong  28672 B
    __shared__ __align__(16) unsigned short HIDb[2 * 7 * 512];      // hidden       14336 B
    __shared__ __align__(16) unsigned short SAb[2 * 2 * 512];       // s|a k0..35    4096 B
    __shared__ __align__(16) float STG_Z[ROWS * 30];                // stoch fp32    3840 B
    __shared__ __align__(16) float NZb[ROWS * 30];                  // noise stage   3840 B
    __shared__ __align__(16) unsigned short W1L[N_W1];              // W1 in LDS    93184 B
    // total 147968 B <= 163840

    const int tid = threadIdx.x;
    const int w = tid >> 6, lane = tid & 63;
    const int col = lane & 15, kg = lane >> 4;
    const int brow0 = blockIdx.x * ROWS;
    const int jt0 = w;
    const int jt1 = (w < 5) ? (w + 8) : -1;    // 13 tiles over 8 waves

    const unsigned short* WR  = W + OFF_R;
    const unsigned short* WZ  = W + OFF_Z;
    const unsigned short* WNI = W + OFF_NI;
    const unsigned short* WNH = W + OFF_NH;
    const unsigned short* W1w = W + OFF_W1;
    const unsigned short* WMV = W + OFF_MV;
    const float* CB = (const float*)(W + W_TOTAL);
    float* out_states = out;
    float* out_stoch  = out + (size_t)T_STEPS * BATCH * 200;

    // ---- hoisted per-jt biases ----
    float brv[2] = {0.f, 0.f}, bzv[2] = {0.f, 0.f}, biv[2] = {0.f, 0.f};
    float bhv[2] = {0.f, 0.f}, b1v[2] = {0.f, 0.f};
    #pragma unroll
    for (int ji = 0; ji < 2; ++ji) {
        const int jt = ji ? jt1 : jt0;
        if (jt < 0) continue;
        const int j = jt * 16 + col;
        if (j < 200) {
            brv[ji] = CB[j];
            bzv[ji] = CB[208 + j];
            biv[ji] = CB[416 + j];
            bhv[ji] = b_hh[400 + j];
            b1v[ji] = b1[j];
        }
    }
    float bmuv = 0.f, bvav = 0.f;
    if (w < 4) {
        const int jm = (w & 1) * 16 + col;
        if (jm < 30) { bmuv = bmu[jm]; bvav = bvar[jm]; }
    }

    // ---- init: zero LDS (pad slots must be 0), copy W1 to LDS, load h0/s0/a0 ----
    for (int i = tid; i < 2 * 7 * 512; i += THREADS) { Hb[0][i] = 0; Hb[1][i] = 0; }
    for (int i = tid; i < 2 * 7 * 512; i += THREADS) HIDb[i] = 0;
    for (int i = tid; i < 2 * 2 * 512; i += THREADS) SAb[i] = 0;
    {
        const u32x4* s1 = reinterpret_cast<const u32x4*>(W1w);
        u32x4* d1 = reinterpret_cast<u32x4*>(W1L);
        for (int i = tid; i < N_W1 / 8; i += THREADS) d1[i] = s1[i];
    }
    __syncthreads();
    for (int i = tid; i < ROWS * 200; i += THREADS) {
        int r = i / 200, jj = i % 200;
        Hb[0][((r >> 4) * 7 + (jj >> 5)) * 512 + fragSlot(r & 15, jj)] =
            f2b(h0[(size_t)(brow0 + r) * 200 + jj]);
    }
    for (int i = tid; i < ROWS * 30; i += THREADS) {
        int r = i / 30, jj = i % 30;
        SAb[((r >> 4) * 2) * 512 + fragSlot(r & 15, jj)] =
            f2b(s0[(size_t)(brow0 + r) * 30 + jj]);
    }
    for (int i = tid; i < ROWS * 6; i += THREADS) {
        int r = i / 6, c = i % 6, k = 30 + c;
        SAb[((r >> 4) * 2 + (k >> 5)) * 512 + fragSlot(r & 15, k)] =
            f2b(ld_nt(&actions[(size_t)(brow0 + r) * 6 + c]));
    }
    __syncthreads();

    for (int t = 0; t < T_STEPS; ++t) {
        const int cur = t & 1, nxt = cur ^ 1;

        // ---------- Phase A ----------
        // waves 5-7 (single-tile): issue ALL global stores first so they retire
        // under phase A's long compute (stoch(t-1) + states(t-1) from Hb[cur]),
        // plus stage noise(t) -> LDS.
        if (jt1 < 0) {
            const int idx = (w - 5) * 64 + lane;   // 0..191
            if (t >= 1) {
                float* dstz = out_stoch + ((size_t)(t - 1) * BATCH + brow0) * 30;
                for (int i = idx; i < 240; i += 192) {
                    f32x4 v = *reinterpret_cast<const f32x4*>(&STG_Z[i * 4]);
                    st_nt4(dstz + i * 4, v);
                }
                // states(t-1) lives in Hb[cur] (fragment layout), stable during phase A
                float* dsts = out_states + ((size_t)(t - 1) * BATCH + brow0) * 200;
                for (int i = idx; i < 1600; i += 192) {
                    const int e0 = i * 4;
                    const int r = e0 / 200, j0 = e0 % 200;       // j0 % 4 == 0
                    const int mt = r >> 4, rr = r & 15;
                    u16x4 hv4 = *reinterpret_cast<const u16x4*>(
                        &Hb[cur][(mt * 7 + (j0 >> 5)) * 512 + fragSlot(rr, j0)]);
                    f32x4 v;
                    v[0] = b2f(hv4[0]); v[1] = b2f(hv4[1]);
                    v[2] = b2f(hv4[2]); v[3] = b2f(hv4[3]);
                    st_nt4(dsts + e0, v);
                }
            }
            const float* np = noise + ((size_t)t * BATCH + brow0) * 30;
            for (int i = idx; i < ROWS * 30; i += 192)
                NZb[i] = ld_nt(&np[i]);
        }
        // gates over K=[s|a|pad|h]; h_new -> Hb[nxt]
        #pragma unroll
        for (int ji = 0; ji < 2; ++ji) {
            const int jt = ji ? jt1 : jt0;
            if (jt < 0) continue;
            // prefetch this tile's 27 weight frags (from L2)
            bf16x8 wRr[9], wZr[9], wNi[2], wNh[7];
            #pragma unroll
            for (int ks = 0; ks < 9; ++ks) {
                wRr[ks] = *reinterpret_cast<const bf16x8*>(&WR[(size_t)(jt * 9 + ks) * 512 + lane * 8]);
                wZr[ks] = *reinterpret_cast<const bf16x8*>(&WZ[(size_t)(jt * 9 + ks) * 512 + lane * 8]);
            }
            #pragma unroll
            for (int ks = 0; ks < 2; ++ks)
                wNi[ks] = *reinterpret_cast<const bf16x8*>(&WNI[(size_t)(jt * 2 + ks) * 512 + lane * 8]);
            #pragma unroll
            for (int ks = 0; ks < 7; ++ks)
                wNh[ks] = *reinterpret_cast<const bf16x8*>(&WNH[(size_t)(jt * 7 + ks) * 512 + lane * 8]);

            // accumulators seeded with composed biases
            f32x4 aR[2], aZ[2], aNi[2], aNh[2];
            #pragma unroll
            for (int mt = 0; mt < 2; ++mt) {
                aR[mt]  = (f32x4){brv[ji], brv[ji], brv[ji], brv[ji]};
                aZ[mt]  = (f32x4){bzv[ji], bzv[ji], bzv[ji], bzv[ji]};
                aNi[mt] = (f32x4){biv[ji], biv[ji], biv[ji], biv[ji]};
                aNh[mt] = (f32x4){bhv[ji], bhv[ji], bhv[ji], bhv[ji]};
            }
            #pragma unroll
            for (int ks = 0; ks < 9; ++ks) {
                #pragma unroll
                for (int mt = 0; mt < 2; ++mt) {
                    bf16x8 a = (ks < 2)
                        ? *reinterpret_cast<const bf16x8*>(&SAb[(mt * 2 + ks) * 512 + lane * 8])
                        : *reinterpret_cast<const bf16x8*>(&Hb[cur][(mt * 7 + (ks - 2)) * 512 + lane * 8]);
                    aR[mt] = MFMA(a, wRr[ks], aR[mt]);
                    aZ[mt] = MFMA(a, wZr[ks], aZ[mt]);
                    if (ks < 2) aNi[mt] = MFMA(a, wNi[ks], aNi[mt]);
                    else        aNh[mt] = MFMA(a, wNh[ks - 2], aNh[mt]);
                }
            }
            // elementwise + h_new
            const int j = jt * 16 + col;
            const bool jv = (j < 200);
            #pragma unroll
            for (int mt = 0; mt < 2; ++mt) {
                #pragma unroll
                for (int q = 0; q < 4; ++q) {
                    const int r0 = kg * 4 + q;
                    const int slot = (j >> 5) * 512 + fragSlot(r0, j);
                    float rg = sigmf(aR[mt][q]);
                    float zg = sigmf(aZ[mt][q]);
                    float ng = tanh_fast(aNi[mt][q] + rg * aNh[mt][q]);
                    if (jv) {
                        float hv = b2f(Hb[cur][mt * 7 * 512 + slot]);
                        float hn = ng + zg * (hv - ng);
                        Hb[nxt][mt * 7 * 512 + slot] = f2b(hn);
                    }
                }
            }
        }
        __syncthreads();

        // ---------- Phase B: hid = relu(h_new @ W1^T + b1) -> HIDb (weights from LDS) ----------
        #pragma unroll
        for (int ji = 0; ji < 2; ++ji) {
            const int jt = ji ? jt1 : jt0;
            if (jt < 0) continue;
            f32x4 c0 = {b1v[ji], b1v[ji], b1v[ji], b1v[ji]};
            f32x4 c1 = {b1v[ji], b1v[ji], b1v[ji], b1v[ji]};
            #pragma unroll
            for (int ks = 0; ks < 7; ++ks) {
                bf16x8 wbv = *reinterpret_cast<const bf16x8*>(&W1L[(size_t)(jt * 7 + ks) * 512 + lane * 8]);
                bf16x8 a0 = *reinterpret_cast<const bf16x8*>(&Hb[nxt][(0 * 7 + ks) * 512 + lane * 8]);
                bf16x8 a1 = *reinterpret_cast<const bf16x8*>(&Hb[nxt][(1 * 7 + ks) * 512 + lane * 8]);
                c0 = MFMA(a0, wbv, c0);
                c1 = MFMA(a1, wbv, c1);
            }
            const int j = jt * 16 + col;
            #pragma unroll
            for (int q = 0; q < 4; ++q) {
                HIDb[(0 * 7 + (j >> 5)) * 512 + fragSlot(kg * 4 + q, j)] = f2b(fmaxf(c0[q], 0.f));
                HIDb[(1 * 7 + (j >> 5)) * 512 + fragSlot(kg * 4 + q, j)] = f2b(fmaxf(c1[q], 0.f));
            }
        }
        __syncthreads();

        // ---------- Phase C: waves 0-3 mu/var -> s_new ; waves 4-7 prefetch actions ----------
        if (w < 4) {
            const int mt = w >> 1, ntile = w & 1;
            bf16x8 wm[7], wv[7];
            #pragma unroll
            for (int ks = 0; ks < 7; ++ks) {
                wm[ks] = *reinterpret_cast<const bf16x8*>(&WMV[(size_t)(ntile * 7 + ks) * 512 + lane * 8]);
                wv[ks] = *reinterpret_cast<const bf16x8*>(&WMV[(size_t)((2 + ntile) * 7 + ks) * 512 + lane * 8]);
            }
            f32x4 cm = {bmuv, bmuv, bmuv, bmuv};
            f32x4 cv = {bvav, bvav, bvav, bvav};
            #pragma unroll
            for (int ks = 0; ks < 7; ++ks) {
                bf16x8 a = *reinterpret_cast<const bf16x8*>(&HIDb[(mt * 7 + ks) * 512 + lane * 8]);
                cm = MFMA(a, wm[ks], cm);
                cv = MFMA(a, wv[ks], cv);
            }
            const int jm = ntile * 16 + col;
            const bool jmv = (jm < 30);
            #pragma unroll
            for (int q = 0; q < 4; ++q) {
                const int r0 = kg * 4 + q;
                const int row = mt * 16 + r0;
                float mu = cm[q];
                float vr = cv[q];
                float var = ((vr > 20.f) ? vr : log1pf(__expf(vr))) + 0.1f;
                if (jmv) {
                    float eps = NZb[row * 30 + jm];
                    float sn = mu + var * eps;
                    STG_Z[row * 30 + jm] = sn;
                    SAb[(mt * 2) * 512 + fragSlot(r0, jm)] = f2b(sn);
                }
            }
        } else {
            const int di = (w - 4) * 64 + lane;   // 0..255
            // prefetch actions(t+1) only — no global stores near this barrier
            if (t + 1 < T_STEPS && di < ROWS * 6) {
                const int r = di / 6, c = di % 6, k = 30 + c;
                float av = ld_nt(&actions[((size_t)(t + 1) * BATCH + brow0 + r) * 6 + c]);
                SAb[((r >> 4) * 2 + (k >> 5)) * 512 + fragSlot(r & 15, k)] = f2b(av);
            }
        }
        __syncthreads();
    }

    // ---- tail: drain states(T-1) from Hb[T_STEPS & 1] and stoch(T-1) ----
    {
        const int fin = T_STEPS & 1;   // buffer holding h_new of step T-1
        float* dsts = out_states + ((size_t)(T_STEPS - 1) * BATCH + brow0) * 200;
        for (int i = tid; i < 1600; i += THREADS) {
            const int e0 = i * 4;
            const int r = e0 / 200, j0 = e0 % 200;
            const int mt = r >> 4, rr = r & 15;
            u16x4 hv4 = *reinterpret_cast<const u16x4*>(
                &Hb[fin][(mt * 7 + (j0 >> 5)) * 512 + fragSlot(rr, j0)]);
            f32x4 v;
            v[0] = b2f(hv4[0]); v[1] = b2f(hv4[1]);
            v[2] = b2f(hv4[2]); v[3] = b2f(hv4[3]);
            st_nt4(dsts + e0, v);
        }
        if (tid < 240) {
            f32x4 v = *reinterpret_cast<const f32x4*>(&STG_Z[tid * 4]);
            st_nt4(out_stoch + ((size_t)(T_STEPS - 1) * BATCH + brow0) * 30 + tid * 4, v);
        }
    }
}

extern "C" void kernel_launch(void* const* d_in, const int* in_sizes, int n_in,
                              void* d_out, int out_size, void* d_ws, size_t ws_size,
                              hipStream_t stream)
{
    const float* actions = (const float*)d_in[0];
    const float* h0      = (const float*)d_in[1];
    const float* s0      = (const float*)d_in[2];
    const float* noise   = (const float*)d_in[3];
    const float* Wfc     = (const float*)d_in[4];
    const float* bfc     = (const float*)d_in[5];
    const float* Wih     = (const float*)d_in[6];
    const float* bih     = (const float*)d_in[7];
    const float* Whh     = (const float*)d_in[8];
    const float* bhh     = (const float*)d_in[9];
    const float* W1      = (const float*)d_in[10];
    const float* b1      = (const float*)d_in[11];
    const float* Wmu     = (const float*)d_in[12];
    const float* bmu     = (const float*)d_in[13];
    const float* Wvar    = (const float*)d_in[14];
    const float* bvar    = (const float*)d_in[15];

    unsigned short* wbuf = (unsigned short*)d_ws;
    float* cb = (float*)(wbuf + W_TOTAL);

    rssm_prep<<<(W_TOTAL + 255) / 256, 256, 0, stream>>>(Wfc, Wih, Whh, W1, Wmu, Wvar, wbuf);
    rssm_bias<<<10, 64, 0, stream>>>(Wih, bfc, bih, bhh, cb);
    rssm_main<<<NBLK, THREADS, 0, stream>>>(actions, h0, s0, noise, bhh, b1,
                                            bmu, bvar, wbuf, (float*)d_out);
}